// Round 3
// baseline (670.829 us; speedup 1.0000x reference)
//
#include <hip/hip_runtime.h>
#include <hip/hip_bf16.h>
#include <stdint.h>

typedef __bf16 bf16;
typedef __bf16 bf16x4 __attribute__((ext_vector_type(4)));
typedef __bf16 bf16x8 __attribute__((ext_vector_type(8)));
typedef float  f32x4  __attribute__((ext_vector_type(4)));

#define MFMA16(a, b, c) __builtin_amdgcn_mfma_f32_16x16x32_bf16((a), (b), (c), 0, 0, 0)
#define EXP2(x) __builtin_amdgcn_exp2f(x)

__device__ __forceinline__ void gload_lds16(const void* g, void* l) {
  __builtin_amdgcn_global_load_lds((const __attribute__((address_space(1))) void*)g,
                                   (__attribute__((address_space(3))) void*)l,
                                   16, 0, 0);
}

// ---------------------------------------------------------------- prep kernels

__global__ __launch_bounds__(256) void k_cast(const float4* __restrict__ in,
                                              bf16x4* __restrict__ out, int n4) {
  int i = blockIdx.x * 256 + threadIdx.x;
  if (i < n4) {
    float4 v = in[i];
    bf16x4 o = {(bf16)v.x, (bf16)v.y, (bf16)v.z, (bf16)v.w};
    out[i] = o;
  }
}

// in[K][N] (fp32) -> out[N][K] (bf16)
__global__ __launch_bounds__(256) void k_transpose(const float* __restrict__ in,
                                                   bf16* __restrict__ out,
                                                   int K, int N) {
  __shared__ float tile[32][33];
  int n0 = blockIdx.x * 32, k0 = blockIdx.y * 32;
  int tx = threadIdx.x, ty = threadIdx.y;  // (32,8)
#pragma unroll
  for (int i = 0; i < 4; ++i)
    tile[ty + i * 8][tx] = in[(size_t)(k0 + ty + i * 8) * N + n0 + tx];
  __syncthreads();
#pragma unroll
  for (int i = 0; i < 4; ++i)
    out[(size_t)(n0 + ty + i * 8) * K + k0 + tx] = (bf16)tile[tx][ty + i * 8];
}

// ---------------------------------------------------------------- 128x128 GEMM core
// C[M,N] = A[M,1024] @ Bt[N,1024]^T, 4 waves (2x2), each wave 64x64, BK=32.

template <typename Epi>
__device__ __forceinline__ void gemm128(const bf16* __restrict__ A,
                                        const bf16* __restrict__ Bt, Epi epi) {
  __shared__ alignas(16) bf16 As[128][32];
  __shared__ alignas(16) bf16 Bs[128][32];
  const int tid = threadIdx.x;
  const int lane = tid & 63, wv = tid >> 6;
  const int l16 = lane & 15, q4 = lane >> 4;
  const int bm = blockIdx.x * 128, bn = blockIdx.y * 128;
  const int wm = (wv >> 1) * 64, wn = (wv & 1) * 64;

  const f32x4 Z4 = {0.f, 0.f, 0.f, 0.f};
  f32x4 acc[4][4];
#pragma unroll
  for (int mi = 0; mi < 4; ++mi)
#pragma unroll
    for (int ni = 0; ni < 4; ++ni) acc[mi][ni] = Z4;

  const int srow = wv * 32 + (lane >> 2);    // staging row (c=0)
  const int scol = (lane & 3) * 8;           // staging col (elements)
  const bf16* ga = A + (size_t)(bm + srow) * 1024 + scol;
  const bf16* gb = Bt + (size_t)(bn + srow) * 1024 + scol;

  for (int k0 = 0; k0 < 1024; k0 += 32) {
    __syncthreads();  // previous iter's LDS reads done
#pragma unroll
    for (int c = 0; c < 2; ++c) {
      gload_lds16(ga + (size_t)c * 16 * 1024 + k0, &As[wv * 32 + c * 16][0]);
      gload_lds16(gb + (size_t)c * 16 * 1024 + k0, &Bs[wv * 32 + c * 16][0]);
    }
    __syncthreads();  // staging complete (compiler drains vmcnt)

    bf16x8 af[4], bfr[4];
#pragma unroll
    for (int i = 0; i < 4; ++i) {
      af[i]  = *(const bf16x8*)&As[wm + i * 16 + l16][q4 * 8];
      bfr[i] = *(const bf16x8*)&Bs[wn + i * 16 + l16][q4 * 8];
    }
#pragma unroll
    for (int mi = 0; mi < 4; ++mi)
#pragma unroll
      for (int ni = 0; ni < 4; ++ni)
        acc[mi][ni] = MFMA16(af[mi], bfr[ni], acc[mi][ni]);
  }

#pragma unroll
  for (int mi = 0; mi < 4; ++mi)
#pragma unroll
    for (int ni = 0; ni < 4; ++ni)
#pragma unroll
      for (int r = 0; r < 4; ++r) {
        int m = bm + wm + mi * 16 + q4 * 4 + r;
        int n = bn + wn + ni * 16 + l16;
        epi(m, n, acc[mi][ni][r]);
      }
}

// QKV GEMM: n<1024 -> Q (scaled into log2 domain), n<2048 -> K, else -> V transposed.
// Q scale = HEAD_DIM^-0.5 * log2(e) so attention can use exp2 directly.
#define QSCALE (0.125f * 1.44269504088896f)

__global__ __launch_bounds__(256) void k_gemm_qkv(const bf16* __restrict__ xb,
                                                  const bf16* __restrict__ wt,
                                                  bf16* __restrict__ Q,
                                                  bf16* __restrict__ Kd,
                                                  bf16* __restrict__ Vt) {
  gemm128(xb, wt, [=](int m, int n, float v) {
    int b = m >> 11, s = m & 2047;
    int sect = n >> 10, nn = n & 1023;
    int h = nn >> 6, d = nn & 63;
    size_t bh = (size_t)b * 16 + h;
    if (sect == 0)
      Q[(bh * 2048 + s) * 64 + d] = (bf16)(v * QSCALE);
    else if (sect == 1)
      Kd[(bh * 2048 + s) * 64 + d] = (bf16)v;
    else
      Vt[(bh * 64 + d) * 2048 + s] = (bf16)v;
  });
}

// Out GEMM: fp32 output + bias.
__global__ __launch_bounds__(256) void k_gemm_out(const bf16* __restrict__ o2,
                                                  const bf16* __restrict__ wt,
                                                  const float* __restrict__ bias,
                                                  float* __restrict__ out) {
  gemm128(o2, wt, [=](int m, int n, float v) {
    out[(size_t)m * 1024 + n] = v + bias[n];
  });
}

// ---------------------------------------------------------------- flash attention
// Grid (32, 64): x = q-tile of 64 rows, y = (b,h). 4 waves, each owns 16 q-rows
// (16 rows/wave -> 8192 waves -> 8 waves/SIMD for latency hiding).
//
// SWAPPED formulation:
//   S^T = mfma(K, Q)   -> lane owns ONE q-row (q = l16); row max/sum are
//                         15 in-lane ops + 2 shfl_xor.
//   O^T = mfma(V^T, P) -> rescale factor f and final 1/l are per-lane scalars.
// P routed through per-wave LDS: packed bf16x4 ds_write_b64, slot ^= (row&14)
// swizzle (bit0 preserved so the b128 read keeps kpos order; bank-balanced).

__global__ __launch_bounds__(256, 8) void k_attn(const bf16* __restrict__ Q,
                                                 const bf16* __restrict__ Kd,
                                                 const bf16* __restrict__ Vt,
                                                 bf16* __restrict__ out2) {
  __shared__ alignas(16) bf16 P_lds[4][16][64];
  const int tid = threadIdx.x, lane = tid & 63, wv = tid >> 6;
  const int l16 = lane & 15, q4 = lane >> 4;
  const int bh = blockIdx.y;
  const int b = bh >> 4, h = bh & 15;
  const int q0 = blockIdx.x * 64 + wv * 16;

  // Q fragments in registers for the whole kernel (B-operand role).
  bf16x8 qf[2];
#pragma unroll
  for (int kk = 0; kk < 2; ++kk)
    qf[kk] = *(const bf16x8*)(Q + ((size_t)bh * 2048 + q0 + l16) * 64 + kk * 32 + q4 * 8);

  const f32x4 Z4 = {0.f, 0.f, 0.f, 0.f};
  float m_r = -__builtin_inff(), l_r = 0.f;
  f32x4 acc_o[4];  // [df]: O^T tile, rows d = df*16+q4*4+r, col q = l16
#pragma unroll
  for (int df = 0; df < 4; ++df) acc_o[df] = Z4;

  const bf16* Kbase = Kd + (size_t)bh * 2048 * 64;
  const bf16* Vbase = Vt + (size_t)bh * 64 * 2048;

  for (int kt = 0; kt < 32; ++kt) {
    // ---- S^T = K @ Q^T  (A = K rows = kpos, B = Q cols = q; Q pre-scaled)
    f32x4 s_acc[4];  // [nf]: rows kpos = nf*16+q4*4+r, col q = l16
#pragma unroll
    for (int nf = 0; nf < 4; ++nf) s_acc[nf] = Z4;
#pragma unroll
    for (int kk = 0; kk < 2; ++kk)
#pragma unroll
      for (int nf = 0; nf < 4; ++nf) {
        bf16x8 kf = *(const bf16x8*)(Kbase + (size_t)(kt * 64 + nf * 16 + l16) * 64 +
                                     kk * 32 + q4 * 8);
        s_acc[nf] = MFMA16(kf, qf[kk], s_acc[nf]);
      }

    // ---- online softmax, one q-row per lane (log2 domain, raw v_exp_f32)
    float t = s_acc[0][0];
#pragma unroll
    for (int nf = 0; nf < 4; ++nf)
#pragma unroll
      for (int r = 0; r < 4; ++r)
        if (nf | r) t = fmaxf(t, s_acc[nf][r]);
    t = fmaxf(t, __shfl_xor(t, 16));
    t = fmaxf(t, __shfl_xor(t, 32));
    float mn = fmaxf(m_r, t);
    float f = EXP2(m_r - mn);
    float ps = 0.f;
#pragma unroll
    for (int nf = 0; nf < 4; ++nf) {
      float pv0 = EXP2(s_acc[nf][0] - mn);
      float pv1 = EXP2(s_acc[nf][1] - mn);
      float pv2 = EXP2(s_acc[nf][2] - mn);
      float pv3 = EXP2(s_acc[nf][3] - mn);
      ps += (pv0 + pv1) + (pv2 + pv3);
      bf16x4 pk = {(bf16)pv0, (bf16)pv1, (bf16)pv2, (bf16)pv3};
      int slot = (nf * 4 + q4) ^ (l16 & 14);  // 8B slots, bit0-preserving swizzle
      *(bf16x4*)&P_lds[wv][l16][slot * 4] = pk;
    }
    ps += __shfl_xor(ps, 16);
    ps += __shfl_xor(ps, 32);
    l_r = l_r * f + ps;
    m_r = mn;
#pragma unroll
    for (int df = 0; df < 4; ++df) acc_o[df] *= f;

    // ---- O^T += V^T @ P^T  (A = V^T rows = d, B = P cols = q, from LDS)
#pragma unroll
    for (int kk2 = 0; kk2 < 2; ++kk2) {
      int pbase = ((kk2 * 8 + q4 * 2) ^ (l16 & 14)) * 4;
      bf16x8 pf = *(const bf16x8*)&P_lds[wv][l16][pbase];
#pragma unroll
      for (int df = 0; df < 4; ++df) {
        bf16x8 vf = *(const bf16x8*)(Vbase + (size_t)(df * 16 + l16) * 2048 +
                                     kt * 64 + kk2 * 32 + q4 * 8);
        acc_o[df] = MFMA16(vf, pf, acc_o[df]);
      }
    }
  }

  // ---- normalize + store with the reference's reshape quirk:
  // (b,h,s,d) -> out2[b][h*128 + s/16][(s%16)*64 + d]
  float inv = 1.0f / l_r;
  int s = q0 + l16;
  int row2 = h * 128 + (s >> 4);
  size_t base = ((size_t)b * 2048 + row2) * 1024 + (s & 15) * 64;
#pragma unroll
  for (int df = 0; df < 4; ++df)
#pragma unroll
    for (int r = 0; r < 4; ++r) {
      int d = df * 16 + q4 * 4 + r;
      out2[base + d] = (bf16)(acc_o[df][r] * inv);
    }
}

// ---------------------------------------------------------------- launch

extern "C" void kernel_launch(void* const* d_in, const int* in_sizes, int n_in,
                              void* d_out, int out_size, void* d_ws, size_t ws_size,
                              hipStream_t stream) {
  const float* x     = (const float*)d_in[0];
  const float* w_qkv = (const float*)d_in[1];
  const float* w_out = (const float*)d_in[2];
  const float* b_out = (const float*)d_in[3];
  float* out = (float*)d_out;

  char* ws = (char*)d_ws;
  size_t off = 0;
  auto alloc = [&](size_t bytes) {
    void* p = ws + off;
    off += (bytes + 255) & ~(size_t)255;
    return p;
  };
  bf16* xb    = (bf16*)alloc((size_t)8192 * 1024 * 2);  // reused as out2 later
  bf16* wqkvT = (bf16*)alloc((size_t)3072 * 1024 * 2);
  bf16* woutT = (bf16*)alloc((size_t)1024 * 1024 * 2);
  bf16* Q     = (bf16*)alloc((size_t)64 * 2048 * 64 * 2);
  bf16* Kd    = (bf16*)alloc((size_t)64 * 2048 * 64 * 2);
  bf16* Vt    = (bf16*)alloc((size_t)64 * 64 * 2048 * 2);
  bf16* out2  = xb;  // xb consumed by k_gemm_qkv before k_attn writes out2

  k_cast<<<8192, 256, 0, stream>>>((const float4*)x, (bf16x4*)xb, 8192 * 1024 / 4);
  k_transpose<<<dim3(96, 32), dim3(32, 8), 0, stream>>>(w_qkv, wqkvT, 1024, 3072);
  k_transpose<<<dim3(32, 32), dim3(32, 8), 0, stream>>>(w_out, woutT, 1024, 1024);
  k_gemm_qkv<<<dim3(64, 24), 256, 0, stream>>>(xb, wqkvT, Q, Kd, Vt);
  k_attn<<<dim3(32, 64), 256, 0, stream>>>(Q, Kd, Vt, out2);
  k_gemm_out<<<dim3(64, 8), 256, 0, stream>>>(out2, woutT, b_out, out);
}

// Round 4
// 443.352 us; speedup vs baseline: 1.5131x; 1.5131x over previous
//
#include <hip/hip_runtime.h>
#include <hip/hip_bf16.h>
#include <stdint.h>

typedef __bf16 bf16;
typedef __bf16 bf16x4 __attribute__((ext_vector_type(4)));
typedef __bf16 bf16x8 __attribute__((ext_vector_type(8)));
typedef float  f32x4  __attribute__((ext_vector_type(4)));

#define MFMA16(a, b, c) __builtin_amdgcn_mfma_f32_16x16x32_bf16((a), (b), (c), 0, 0, 0)
#define EXP2(x) __builtin_amdgcn_exp2f(x)

__device__ __forceinline__ void gload_lds16(const void* g, void* l) {
  __builtin_amdgcn_global_load_lds((const __attribute__((address_space(1))) void*)g,
                                   (__attribute__((address_space(3))) void*)l,
                                   16, 0, 0);
}

// ---------------------------------------------------------------- prep kernels

__global__ __launch_bounds__(256) void k_cast(const float4* __restrict__ in,
                                              bf16x4* __restrict__ out, int n4) {
  int i = blockIdx.x * 256 + threadIdx.x;
  if (i < n4) {
    float4 v = in[i];
    bf16x4 o = {(bf16)v.x, (bf16)v.y, (bf16)v.z, (bf16)v.w};
    out[i] = o;
  }
}

// in[K][N] (fp32) -> out[N][K] (bf16)
__global__ __launch_bounds__(256) void k_transpose(const float* __restrict__ in,
                                                   bf16* __restrict__ out,
                                                   int K, int N) {
  __shared__ float tile[32][33];
  int n0 = blockIdx.x * 32, k0 = blockIdx.y * 32;
  int tx = threadIdx.x, ty = threadIdx.y;  // (32,8)
#pragma unroll
  for (int i = 0; i < 4; ++i)
    tile[ty + i * 8][tx] = in[(size_t)(k0 + ty + i * 8) * N + n0 + tx];
  __syncthreads();
#pragma unroll
  for (int i = 0; i < 4; ++i)
    out[(size_t)(n0 + ty + i * 8) * K + k0 + tx] = (bf16)tile[tx][ty + i * 8];
}

// ---------------------------------------------------------------- 128x128 GEMM core
// C[M,N] = A[M,1024] @ Bt[N,1024]^T, 4 waves (2x2), each wave 64x64, BK=32.

template <typename Epi>
__device__ __forceinline__ void gemm128(const bf16* __restrict__ A,
                                        const bf16* __restrict__ Bt, Epi epi) {
  __shared__ alignas(16) bf16 As[128][32];
  __shared__ alignas(16) bf16 Bs[128][32];
  const int tid = threadIdx.x;
  const int lane = tid & 63, wv = tid >> 6;
  const int l16 = lane & 15, q4 = lane >> 4;
  const int bm = blockIdx.x * 128, bn = blockIdx.y * 128;
  const int wm = (wv >> 1) * 64, wn = (wv & 1) * 64;

  const f32x4 Z4 = {0.f, 0.f, 0.f, 0.f};
  f32x4 acc[4][4];
#pragma unroll
  for (int mi = 0; mi < 4; ++mi)
#pragma unroll
    for (int ni = 0; ni < 4; ++ni) acc[mi][ni] = Z4;

  const int srow = wv * 32 + (lane >> 2);    // staging row (c=0)
  const int scol = (lane & 3) * 8;           // staging col (elements)
  const bf16* ga = A + (size_t)(bm + srow) * 1024 + scol;
  const bf16* gb = Bt + (size_t)(bn + srow) * 1024 + scol;

  for (int k0 = 0; k0 < 1024; k0 += 32) {
    __syncthreads();  // previous iter's LDS reads done
#pragma unroll
    for (int c = 0; c < 2; ++c) {
      gload_lds16(ga + (size_t)c * 16 * 1024 + k0, &As[wv * 32 + c * 16][0]);
      gload_lds16(gb + (size_t)c * 16 * 1024 + k0, &Bs[wv * 32 + c * 16][0]);
    }
    __syncthreads();  // staging complete (compiler drains vmcnt)

    bf16x8 af[4], bfr[4];
#pragma unroll
    for (int i = 0; i < 4; ++i) {
      af[i]  = *(const bf16x8*)&As[wm + i * 16 + l16][q4 * 8];
      bfr[i] = *(const bf16x8*)&Bs[wn + i * 16 + l16][q4 * 8];
    }
#pragma unroll
    for (int mi = 0; mi < 4; ++mi)
#pragma unroll
      for (int ni = 0; ni < 4; ++ni)
        acc[mi][ni] = MFMA16(af[mi], bfr[ni], acc[mi][ni]);
  }

#pragma unroll
  for (int mi = 0; mi < 4; ++mi)
#pragma unroll
    for (int ni = 0; ni < 4; ++ni)
#pragma unroll
      for (int r = 0; r < 4; ++r) {
        int m = bm + wm + mi * 16 + q4 * 4 + r;
        int n = bn + wn + ni * 16 + l16;
        epi(m, n, acc[mi][ni][r]);
      }
}

// QKV GEMM: n<1024 -> Q (scaled into log2 domain), n<2048 -> K, else -> V transposed.
// Q scale = HEAD_DIM^-0.5 * log2(e) so attention can use exp2 directly.
#define QSCALE (0.125f * 1.44269504088896f)

__global__ __launch_bounds__(256) void k_gemm_qkv(const bf16* __restrict__ xb,
                                                  const bf16* __restrict__ wt,
                                                  bf16* __restrict__ Q,
                                                  bf16* __restrict__ Kd,
                                                  bf16* __restrict__ Vt) {
  gemm128(xb, wt, [=](int m, int n, float v) {
    int b = m >> 11, s = m & 2047;
    int sect = n >> 10, nn = n & 1023;
    int h = nn >> 6, d = nn & 63;
    size_t bh = (size_t)b * 16 + h;
    if (sect == 0)
      Q[(bh * 2048 + s) * 64 + d] = (bf16)(v * QSCALE);
    else if (sect == 1)
      Kd[(bh * 2048 + s) * 64 + d] = (bf16)v;
    else
      Vt[(bh * 64 + d) * 2048 + s] = (bf16)v;
  });
}

// Out GEMM: fp32 output + bias.
__global__ __launch_bounds__(256) void k_gemm_out(const bf16* __restrict__ o2,
                                                  const bf16* __restrict__ wt,
                                                  const float* __restrict__ bias,
                                                  float* __restrict__ out) {
  gemm128(o2, wt, [=](int m, int n, float v) {
    out[(size_t)m * 1024 + n] = v + bias[n];
  });
}

// ---------------------------------------------------------------- flash attention
// Grid (16, 64): x = q-tile of 128 rows, y = (b,h). 4 waves, each owns 32 q-rows.
// NO min-occupancy bound: ILP > TLP here. Each lane needs K(8x16B)+V(8x16B)
// load destinations simultaneously in flight; VGPR starvation (r2: 64, r3: 32)
// serialized the loads (~280cy L2 each) and was the dominant stall.
//
// SWAPPED formulation:
//   S^T = mfma(K, Q)   -> lane owns ONE q-row per mf (q = l16).
//   O^T = mfma(V^T, P) -> rescale and 1/l are per-lane scalars.
// Loads: K first, then V (FIFO vmcnt -> waiting on K leaves V in flight;
// V latency hides under QK+softmax).

__global__ __launch_bounds__(256, 2) void k_attn(const bf16* __restrict__ Q,
                                                 const bf16* __restrict__ Kd,
                                                 const bf16* __restrict__ Vt,
                                                 bf16* __restrict__ out2) {
  __shared__ alignas(16) bf16 P_lds[4][32][64];
  const int tid = threadIdx.x, lane = tid & 63, wv = tid >> 6;
  const int l16 = lane & 15, q4 = lane >> 4;
  const int bh = blockIdx.y;
  const int b = bh >> 4, h = bh & 15;
  const int q0 = blockIdx.x * 128 + wv * 32;

  // Q fragments in registers for the whole kernel (B-operand role).
  bf16x8 qf[2][2];
#pragma unroll
  for (int mf = 0; mf < 2; ++mf)
#pragma unroll
    for (int kk = 0; kk < 2; ++kk)
      qf[mf][kk] = *(const bf16x8*)(Q + ((size_t)bh * 2048 + q0 + mf * 16 + l16) * 64 +
                                    kk * 32 + q4 * 8);

  const f32x4 Z4 = {0.f, 0.f, 0.f, 0.f};
  float m_r[2], l_r[2];
  f32x4 acc_o[2][4];  // [mf][df]: O^T tile, rows d = df*16+q4*4+r, col q = mf*16+l16
#pragma unroll
  for (int mf = 0; mf < 2; ++mf) {
    m_r[mf] = -__builtin_inff();
    l_r[mf] = 0.f;
#pragma unroll
    for (int df = 0; df < 4; ++df) acc_o[mf][df] = Z4;
  }

  const bf16* Kbase = Kd + (size_t)bh * 2048 * 64;
  const bf16* Vbase = Vt + (size_t)bh * 64 * 2048;

  for (int kt = 0; kt < 32; ++kt) {
    // ---- issue ALL K loads, then ALL V loads (K waited first; V stays in flight)
    bf16x8 kf[2][4], vfr[2][4];
#pragma unroll
    for (int kk = 0; kk < 2; ++kk)
#pragma unroll
      for (int nf = 0; nf < 4; ++nf)
        kf[kk][nf] = *(const bf16x8*)(Kbase + (size_t)(kt * 64 + nf * 16 + l16) * 64 +
                                      kk * 32 + q4 * 8);
#pragma unroll
    for (int kk2 = 0; kk2 < 2; ++kk2)
#pragma unroll
      for (int df = 0; df < 4; ++df)
        vfr[kk2][df] = *(const bf16x8*)(Vbase + (size_t)(df * 16 + l16) * 2048 +
                                        kt * 64 + kk2 * 32 + q4 * 8);

    // ---- S^T = K @ Q^T
    f32x4 s_acc[2][4];  // [mf][nf]: rows kpos = nf*16+q4*4+r, col q = mf*16+l16
#pragma unroll
    for (int mf = 0; mf < 2; ++mf)
#pragma unroll
      for (int nf = 0; nf < 4; ++nf) s_acc[mf][nf] = Z4;
    __builtin_amdgcn_s_setprio(1);
#pragma unroll
    for (int kk = 0; kk < 2; ++kk)
#pragma unroll
      for (int nf = 0; nf < 4; ++nf)
#pragma unroll
        for (int mf = 0; mf < 2; ++mf)
          s_acc[mf][nf] = MFMA16(kf[kk][nf], qf[mf][kk], s_acc[mf][nf]);
    __builtin_amdgcn_s_setprio(0);

    // ---- online softmax, one q-row per lane per mf (log2 domain, raw v_exp_f32)
    float fmf[2];
#pragma unroll
    for (int mf = 0; mf < 2; ++mf) {
      float t = s_acc[mf][0][0];
#pragma unroll
      for (int nf = 0; nf < 4; ++nf)
#pragma unroll
        for (int r = 0; r < 4; ++r)
          if (nf | r) t = fmaxf(t, s_acc[mf][nf][r]);
      t = fmaxf(t, __shfl_xor(t, 16));
      t = fmaxf(t, __shfl_xor(t, 32));
      float mn = fmaxf(m_r[mf], t);
      float f = EXP2(m_r[mf] - mn);
      float ps = 0.f;
      const int row = mf * 16 + l16;
#pragma unroll
      for (int nf = 0; nf < 4; ++nf) {
        float pv0 = EXP2(s_acc[mf][nf][0] - mn);
        float pv1 = EXP2(s_acc[mf][nf][1] - mn);
        float pv2 = EXP2(s_acc[mf][nf][2] - mn);
        float pv3 = EXP2(s_acc[mf][nf][3] - mn);
        ps += (pv0 + pv1) + (pv2 + pv3);
        bf16x4 pk = {(bf16)pv0, (bf16)pv1, (bf16)pv2, (bf16)pv3};
        int slot = (nf * 4 + q4) ^ (l16 & 14);  // 8B slots, bit0-preserving swizzle
        *(bf16x4*)&P_lds[wv][row][slot * 4] = pk;
      }
      ps += __shfl_xor(ps, 16);
      ps += __shfl_xor(ps, 32);
      l_r[mf] = l_r[mf] * f + ps;
      m_r[mf] = mn;
      fmf[mf] = f;
    }
#pragma unroll
    for (int mf = 0; mf < 2; ++mf)
#pragma unroll
      for (int df = 0; df < 4; ++df) acc_o[mf][df] *= fmf[mf];

    // ---- O^T += V^T @ P^T  (A = V^T rows = d, B = P cols = q, from LDS)
#pragma unroll
    for (int kk2 = 0; kk2 < 2; ++kk2) {
      bf16x8 pf[2];
#pragma unroll
      for (int mf = 0; mf < 2; ++mf) {
        int row = mf * 16 + l16;
        int pbase = ((kk2 * 8 + q4 * 2) ^ (l16 & 14)) * 4;
        pf[mf] = *(const bf16x8*)&P_lds[wv][row][pbase];
      }
      __builtin_amdgcn_s_setprio(1);
#pragma unroll
      for (int df = 0; df < 4; ++df)
#pragma unroll
        for (int mf = 0; mf < 2; ++mf)
          acc_o[mf][df] = MFMA16(vfr[kk2][df], pf[mf], acc_o[mf][df]);
      __builtin_amdgcn_s_setprio(0);
    }
  }

  // ---- normalize + store with the reference's reshape quirk:
  // (b,h,s,d) -> out2[b][h*128 + s/16][(s%16)*64 + d]
#pragma unroll
  for (int mf = 0; mf < 2; ++mf) {
    float inv = 1.0f / l_r[mf];
    int s = q0 + mf * 16 + l16;
    int row2 = h * 128 + (s >> 4);
    size_t base = ((size_t)b * 2048 + row2) * 1024 + (s & 15) * 64;
#pragma unroll
    for (int df = 0; df < 4; ++df)
#pragma unroll
      for (int r = 0; r < 4; ++r) {
        int d = df * 16 + q4 * 4 + r;
        out2[base + d] = (bf16)(acc_o[mf][df][r] * inv);
      }
  }
}

// ---------------------------------------------------------------- launch

extern "C" void kernel_launch(void* const* d_in, const int* in_sizes, int n_in,
                              void* d_out, int out_size, void* d_ws, size_t ws_size,
                              hipStream_t stream) {
  const float* x     = (const float*)d_in[0];
  const float* w_qkv = (const float*)d_in[1];
  const float* w_out = (const float*)d_in[2];
  const float* b_out = (const float*)d_in[3];
  float* out = (float*)d_out;

  char* ws = (char*)d_ws;
  size_t off = 0;
  auto alloc = [&](size_t bytes) {
    void* p = ws + off;
    off += (bytes + 255) & ~(size_t)255;
    return p;
  };
  bf16* xb    = (bf16*)alloc((size_t)8192 * 1024 * 2);  // reused as out2 later
  bf16* wqkvT = (bf16*)alloc((size_t)3072 * 1024 * 2);
  bf16* woutT = (bf16*)alloc((size_t)1024 * 1024 * 2);
  bf16* Q     = (bf16*)alloc((size_t)64 * 2048 * 64 * 2);
  bf16* Kd    = (bf16*)alloc((size_t)64 * 2048 * 64 * 2);
  bf16* Vt    = (bf16*)alloc((size_t)64 * 64 * 2048 * 2);
  bf16* out2  = xb;  // xb consumed by k_gemm_qkv before k_attn writes out2

  k_cast<<<8192, 256, 0, stream>>>((const float4*)x, (bf16x4*)xb, 8192 * 1024 / 4);
  k_transpose<<<dim3(96, 32), dim3(32, 8), 0, stream>>>(w_qkv, wqkvT, 1024, 3072);
  k_transpose<<<dim3(32, 32), dim3(32, 8), 0, stream>>>(w_out, woutT, 1024, 1024);
  k_gemm_qkv<<<dim3(64, 24), 256, 0, stream>>>(xb, wqkvT, Q, Kd, Vt);
  k_attn<<<dim3(16, 64), 256, 0, stream>>>(Q, Kd, Vt, out2);
  k_gemm_out<<<dim3(64, 8), 256, 0, stream>>>(out2, woutT, b_out, out);
}